// Round 1
// baseline (21661.292 us; speedup 1.0000x reference)
//
#include <hip/hip_runtime.h>
#include <hip/hip_bf16.h>
#include <math.h>

// Problem constants
#define BB 64
#define TT 384
#define CC 512
#define BT 24576           // BB*TT
#define KCODE 1024
#define NQ 6
#define PLANE 196608       // CC*TT per batch (also TT*CC)
#define RSZ 12582912       // BB*CC*TT floats

// ---------------------------------------------------------------------------
// codebook row norms: ||c||^2 for all 18 codebooks (3 streams x 6 q) x 1024
__global__ void k_cnorm(const float* __restrict__ cb0, const float* __restrict__ cb1,
                        const float* __restrict__ cb2, float* __restrict__ cn) {
    int r = blockIdx.x;              // r = s*6144 + q*1024 + n
    int lane = threadIdx.x;          // 64 threads = 1 wave
    int s = r / 6144, rem = r % 6144;
    const float* cb = (s == 0 ? cb0 : (s == 1 ? cb1 : cb2)) + (size_t)rem * 512;
    float a = 0.f;
#pragma unroll
    for (int j = 0; j < 8; ++j) { float v = cb[lane + j * 64]; a = fmaf(v, v, a); }
    for (int o = 32; o; o >>= 1) a += __shfl_down(a, o);
    if (!lane) cn[r] = a;
}

// ---------------------------------------------------------------------------
// permute W_conv (O,I,3) -> B2[o][tap*1024 + ch]
__global__ void k_b2(const float* __restrict__ Wc, float* __restrict__ B2) {
    int g = blockIdx.x * 256 + threadIdx.x;   // < 512*3072
    int o = g / 3072, r2 = g % 3072;
    int tap = r2 / 1024, ch = r2 % 1024;
    B2[g] = Wc[((size_t)o * 1024 + ch) * 3 + tap];
}

// ---------------------------------------------------------------------------
// TC[z] = cb[z] @ W_lin^T + b_lin  (z = s*6+q, s in {body,hands}); 64x64 tiles
__global__ __launch_bounds__(256) void k_tcgemm(const float* __restrict__ cbB,
                                                const float* __restrict__ cbH,
                                                const float* __restrict__ W,
                                                const float* __restrict__ bl,
                                                float* __restrict__ TC) {
    int z = blockIdx.z;
    const float* A = (z < 6 ? cbB : cbH) + (size_t)(z % 6) * 524288;
    float* D = TC + (size_t)z * 524288;
    int m0 = blockIdx.x * 64, n0 = blockIdx.y * 64;
    __shared__ float As[16][68];
    __shared__ float Bs[16][68];
    int tid = threadIdx.x, tx = tid & 15, ty = tid >> 4;
    int mr = tid >> 2, f4 = (tid & 3) * 4;
    float acc[4][4] = {};
    for (int k0 = 0; k0 < 512; k0 += 16) {
        float4 va = *(const float4*)(A + (size_t)(m0 + mr) * 512 + k0 + f4);
        float4 vb = *(const float4*)(W + (size_t)(n0 + mr) * 512 + k0 + f4);
        As[f4 + 0][mr] = va.x; As[f4 + 1][mr] = va.y; As[f4 + 2][mr] = va.z; As[f4 + 3][mr] = va.w;
        Bs[f4 + 0][mr] = vb.x; Bs[f4 + 1][mr] = vb.y; Bs[f4 + 2][mr] = vb.z; Bs[f4 + 3][mr] = vb.w;
        __syncthreads();
#pragma unroll
        for (int kk = 0; kk < 16; ++kk) {
            float4 a = *(float4*)&As[kk][ty * 4];
            float4 b = *(float4*)&Bs[kk][tx * 4];
            float av[4] = {a.x, a.y, a.z, a.w}, bv[4] = {b.x, b.y, b.z, b.w};
#pragma unroll
            for (int r = 0; r < 4; ++r)
#pragma unroll
                for (int c = 0; c < 4; ++c) acc[r][c] = fmaf(av[r], bv[c], acc[r][c]);
        }
        __syncthreads();
    }
    float4 blv = *(const float4*)(bl + n0 + tx * 4);
#pragma unroll
    for (int r = 0; r < 4; ++r) {
        float4 o;
        o.x = acc[r][0] + blv.x; o.y = acc[r][1] + blv.y;
        o.z = acc[r][2] + blv.z; o.w = acc[r][3] + blv.w;
        *(float4*)(D + (size_t)(m0 + ty * 4 + r) * 512 + n0 + tx * 4) = o;
    }
}

// ---------------------------------------------------------------------------
// VQ distance GEMM + fused argmin.
// X layout (BB,512,TT): A[m=(b,t), k=c] is m-contiguous. 128x128x16 tiles,
// 8x8 microtile. B-frag via strided float2 (ds_read_b64) -> conflict-free.
// key[m] = atomicMin over packed ((ordered float bits of cn-2*dot)<<32 | n).
__global__ __launch_bounds__(256) void k_dist(const float* __restrict__ X,
                                              const float* __restrict__ CB,
                                              const float* __restrict__ cn,
                                              unsigned long long* __restrict__ key) {
    __shared__ __align__(16) char smem[16640];
    float (*As)[128] = (float (*)[128])smem;
    float (*Bs)[132] = (float (*)[132])(smem + 8192);
    unsigned long long* red = (unsigned long long*)smem;   // epilogue reuse (16KB)

    int tid = threadIdx.x, tx = tid & 15, ty = tid >> 4;
    int mt = blockIdx.x, b = mt / 3, t0 = (mt % 3) * 128;
    int n0 = blockIdx.y * 128;
    const float* Ab = X + (size_t)b * PLANE + t0;          // A[k][m] = Ab[k*384+m]
    int akr = tid >> 5, af4 = (tid & 31) * 4;
    int bnr = tid >> 2, bf4 = (tid & 3) * 4;

    float4 pa0 = *(const float4*)(Ab + (size_t)akr * 384 + af4);
    float4 pa1 = *(const float4*)(Ab + (size_t)(akr + 8) * 384 + af4);
    float4 pb0 = *(const float4*)(CB + (size_t)(n0 + bnr) * 512 + bf4);
    float4 pb1 = *(const float4*)(CB + (size_t)(n0 + bnr + 64) * 512 + bf4);

    float acc[8][8] = {};
    for (int ks = 0; ks < 32; ++ks) {
        *(float4*)&As[akr][af4] = pa0;
        *(float4*)&As[akr + 8][af4] = pa1;
        Bs[bf4 + 0][bnr] = pb0.x; Bs[bf4 + 1][bnr] = pb0.y;
        Bs[bf4 + 2][bnr] = pb0.z; Bs[bf4 + 3][bnr] = pb0.w;
        Bs[bf4 + 0][bnr + 64] = pb1.x; Bs[bf4 + 1][bnr + 64] = pb1.y;
        Bs[bf4 + 2][bnr + 64] = pb1.z; Bs[bf4 + 3][bnr + 64] = pb1.w;
        __syncthreads();
        if (ks < 31) {
            int k0 = (ks + 1) * 16;
            pa0 = *(const float4*)(Ab + (size_t)(k0 + akr) * 384 + af4);
            pa1 = *(const float4*)(Ab + (size_t)(k0 + akr + 8) * 384 + af4);
            pb0 = *(const float4*)(CB + (size_t)(n0 + bnr) * 512 + k0 + bf4);
            pb1 = *(const float4*)(CB + (size_t)(n0 + bnr + 64) * 512 + k0 + bf4);
        }
#pragma unroll
        for (int kk = 0; kk < 16; ++kk) {
            float4 a0 = *(float4*)&As[kk][ty * 8];
            float4 a1 = *(float4*)&As[kk][ty * 8 + 4];
            float2 b0 = *(float2*)&Bs[kk][tx * 2];
            float2 b1 = *(float2*)&Bs[kk][tx * 2 + 32];
            float2 b2 = *(float2*)&Bs[kk][tx * 2 + 64];
            float2 b3 = *(float2*)&Bs[kk][tx * 2 + 96];
            float av[8] = {a0.x, a0.y, a0.z, a0.w, a1.x, a1.y, a1.z, a1.w};
            float bv[8] = {b0.x, b0.y, b1.x, b1.y, b2.x, b2.y, b3.x, b3.y};
#pragma unroll
            for (int r = 0; r < 8; ++r)
#pragma unroll
                for (int c = 0; c < 8; ++c) acc[r][c] = fmaf(av[r], bv[c], acc[r][c]);
        }
        __syncthreads();
    }
    // epilogue: per-row min of (cn[n] - 2*dot) over this block's 128 n's
    int nloc[8]; float cnv[8];
#pragma unroll
    for (int j = 0; j < 8; ++j) {
        nloc[j] = tx * 2 + (j >> 1) * 32 + (j & 1);       // ascending in j
        cnv[j] = cn[n0 + nloc[j]];
    }
#pragma unroll
    for (int r = 0; r < 8; ++r) {
        float bvv = fmaf(-2.f, acc[r][0], cnv[0]);
        unsigned int bi = (unsigned int)(n0 + nloc[0]);
#pragma unroll
        for (int j = 1; j < 8; ++j) {
            float v = fmaf(-2.f, acc[r][j], cnv[j]);
            if (v < bvv) { bvv = v; bi = (unsigned int)(n0 + nloc[j]); }
        }
        unsigned int fm = __float_as_uint(bvv);
        fm = (fm & 0x80000000u) ? ~fm : (fm | 0x80000000u);   // monotonic float->uint
        red[(ty * 8 + r) * 16 + tx] = ((unsigned long long)fm << 32) | bi;
    }
    __syncthreads();
    if (tid < 128) {
        unsigned long long best = red[tid * 16];
#pragma unroll
        for (int j = 1; j < 16; ++j) {
            unsigned long long v = red[tid * 16 + j];
            best = v < best ? v : best;
        }
        atomicMin(&key[(size_t)b * 384 + t0 + tid], best);
    }
}

// ---------------------------------------------------------------------------
// write float indices to output + histogram for perplexity
__global__ void k_finalize(const unsigned long long* __restrict__ key,
                           float* __restrict__ outIdx, int part, int q,
                           unsigned int* __restrict__ hist) {
    __shared__ unsigned int lh[1024];
    int tid = threadIdx.x;
    for (int j = tid; j < 1024; j += 256) lh[j] = 0;
    __syncthreads();
    int m = blockIdx.x * 256 + tid;
    int b = m / 384, t = m % 384;
    unsigned int idx = (unsigned int)(key[m] & 0xffffffffu);
    outIdx[((size_t)b * 1152 + part * 384 + t) * 6 + q] = (float)idx;
    atomicAdd(&lh[idx], 1u);
    __syncthreads();
    for (int j = tid; j < 1024; j += 256)
        if (lh[j]) atomicAdd(&hist[j], lh[j]);
}

// ---------------------------------------------------------------------------
// residual update + quant accumulation + commit loss.
// X: VQ input (rb or hiera); R: residual state to update (may alias X).
__global__ __launch_bounds__(256) void k_update(const float* X, float* R,
                                                const float* __restrict__ CB,
                                                float* __restrict__ qout, int cbase,
                                                const unsigned long long* __restrict__ key,
                                                float* __restrict__ lossPtr) {
    int bi = blockIdx.x;
    int b = bi / 6, t0 = (bi % 6) * 64;
    int tid = threadIdx.x, tt = tid & 63, cl = tid >> 6;
    int t = t0 + tt;
    unsigned int idx = (unsigned int)(key[(size_t)b * 384 + t] & 0xffffffffu);
    const float* cb = CB + (size_t)idx * 512;
    float commit = 0.f;
    for (int ci = 0; ci < 128; ++ci) {
        int c = ci * 4 + cl;
        size_t xi = ((size_t)b * 512 + c) * 384 + t;
        float code = cb[c];
        float x = X[xi];
        float d = x - code;
        commit = fmaf(d, d, commit);
        R[xi] = R[xi] - code;
        size_t qi = ((size_t)b * 1536 + cbase + c) * 384 + t;
        qout[qi] += code;
    }
    __shared__ float red[256];
    red[tid] = commit; __syncthreads();
    for (int s = 128; s; s >>= 1) { if (tid < s) red[tid] += red[tid + s]; __syncthreads(); }
    if (!tid) atomicAdd(lossPtr, red[0] * (1.f / (12582912.f * 6.f)));
}

// ---------------------------------------------------------------------------
// U[b, t*512+n] = TC[idx[b,t]][n]   (flat per-b buffer; conv views it as (512,384))
__global__ void k_gatherU(const float* __restrict__ TCq,
                          const unsigned long long* __restrict__ key,
                          float* __restrict__ U) {
    size_t g4 = ((size_t)blockIdx.x * 256 + threadIdx.x) * 4;   // < RSZ
    int b = (int)(g4 / PLANE), p = (int)(g4 % PLANE);
    int t = p >> 9, n = p & 511;
    unsigned int idx = (unsigned int)(key[(size_t)b * 384 + t] & 0xffffffffu);
    *(float4*)(U + g4) = *(const float4*)(TCq + (size_t)idx * 512 + n);
}

// ---------------------------------------------------------------------------
// implicit-GEMM conv1d k=3 pad=1 over concat([U-view, R]) channels (1024),
// weights pre-permuted B2[o][tap*1024+ch]. Output (BB,512,TT) + bias.
__global__ __launch_bounds__(256) void k_conv(const float* __restrict__ U,
                                              const float* __restrict__ R,
                                              const float* __restrict__ B2,
                                              const float* __restrict__ bc,
                                              float* __restrict__ Y) {
    __shared__ __align__(16) char smem[16640];
    float (*As)[128] = (float (*)[128])smem;
    float (*Bs)[132] = (float (*)[132])(smem + 8192);

    int tid = threadIdx.x, tx = tid & 15, ty = tid >> 4;
    int mt = blockIdx.x, b = mt / 3, t0 = (mt % 3) * 128;
    int n0 = blockIdx.y * 128;
    int akr = tid >> 5, af4 = (tid & 31) * 4;
    int bnr = tid >> 2, bf4 = (tid & 3) * 4;

    float4 pa0, pa1, pb0, pb1;
    // A element loader: ch in [0,1024), tau may be out of [0,384) -> 0
    auto loadA = [&](int ch, int tbase) {
        const float* src = (ch < 512) ? (U + (size_t)b * PLANE + (size_t)ch * 384)
                                      : (R + ((size_t)b * 512 + (ch - 512)) * 384);
        float4 v;
#pragma unroll
        for (int e = 0; e < 4; ++e) {
            int tu = tbase + e;
            ((float*)&v)[e] = (tu >= 0 && tu < 384) ? src[tu] : 0.f;
        }
        return v;
    };
    {
        int tap = 0, cb0 = 0;
        int tbase = t0 + af4 + tap - 1;
        pa0 = loadA(cb0 + akr, tbase);
        pa1 = loadA(cb0 + akr + 8, tbase);
        pb0 = *(const float4*)(B2 + (size_t)(n0 + bnr) * 3072 + bf4);
        pb1 = *(const float4*)(B2 + (size_t)(n0 + bnr + 64) * 3072 + bf4);
    }
    float acc[8][8] = {};
    for (int ks = 0; ks < 192; ++ks) {
        *(float4*)&As[akr][af4] = pa0;
        *(float4*)&As[akr + 8][af4] = pa1;
        Bs[bf4 + 0][bnr] = pb0.x; Bs[bf4 + 1][bnr] = pb0.y;
        Bs[bf4 + 2][bnr] = pb0.z; Bs[bf4 + 3][bnr] = pb0.w;
        Bs[bf4 + 0][bnr + 64] = pb1.x; Bs[bf4 + 1][bnr + 64] = pb1.y;
        Bs[bf4 + 2][bnr + 64] = pb1.z; Bs[bf4 + 3][bnr + 64] = pb1.w;
        __syncthreads();
        if (ks < 191) {
            int ks1 = ks + 1;
            int tap = ks1 >> 6, cb0 = (ks1 & 63) << 4;
            int tbase = t0 + af4 + tap - 1;
            pa0 = loadA(cb0 + akr, tbase);
            pa1 = loadA(cb0 + akr + 8, tbase);
            pb0 = *(const float4*)(B2 + (size_t)(n0 + bnr) * 3072 + ks1 * 16 + bf4);
            pb1 = *(const float4*)(B2 + (size_t)(n0 + bnr + 64) * 3072 + ks1 * 16 + bf4);
        }
#pragma unroll
        for (int kk = 0; kk < 16; ++kk) {
            float4 a0 = *(float4*)&As[kk][ty * 8];
            float4 a1 = *(float4*)&As[kk][ty * 8 + 4];
            float2 b0 = *(float2*)&Bs[kk][tx * 2];
            float2 b1 = *(float2*)&Bs[kk][tx * 2 + 32];
            float2 b2 = *(float2*)&Bs[kk][tx * 2 + 64];
            float2 b3 = *(float2*)&Bs[kk][tx * 2 + 96];
            float av[8] = {a0.x, a0.y, a0.z, a0.w, a1.x, a1.y, a1.z, a1.w};
            float bv[8] = {b0.x, b0.y, b1.x, b1.y, b2.x, b2.y, b3.x, b3.y};
#pragma unroll
            for (int r = 0; r < 8; ++r)
#pragma unroll
                for (int c = 0; c < 8; ++c) acc[r][c] = fmaf(av[r], bv[c], acc[r][c]);
        }
        __syncthreads();
    }
#pragma unroll
    for (int j = 0; j < 8; ++j) {
        int o = n0 + tx * 2 + (j >> 1) * 32 + (j & 1);
        float bias = bc[o];
        float* dst = Y + ((size_t)b * 512 + o) * 384 + t0 + ty * 8;
        float4 v0, v1;
        v0.x = acc[0][j] + bias; v0.y = acc[1][j] + bias;
        v0.z = acc[2][j] + bias; v0.w = acc[3][j] + bias;
        v1.x = acc[4][j] + bias; v1.y = acc[5][j] + bias;
        v1.z = acc[6][j] + bias; v1.w = acc[7][j] + bias;
        *(float4*)dst = v0; *(float4*)(dst + 4) = v1;
    }
}

// ---------------------------------------------------------------------------
// perplexity: exp(-sum p*log(p+1e-10)) per VQ, accumulated /6
__global__ void k_perp(const unsigned int* __restrict__ hist, float* __restrict__ perpOut) {
    int sq = blockIdx.x, tid = threadIdx.x;
    float acc = 0.f;
    for (int j = tid; j < 1024; j += 256) {
        float p = (float)hist[sq * 1024 + j] * (1.f / 24576.f);
        acc += p * logf(p + 1e-10f);
    }
    __shared__ float red[256];
    red[tid] = acc; __syncthreads();
    for (int s = 128; s; s >>= 1) { if (tid < s) red[tid] += red[tid + s]; __syncthreads(); }
    if (!tid) atomicAdd(perpOut, expf(-red[0]) * (1.f / 6.f));
}

// ---------------------------------------------------------------------------
extern "C" void kernel_launch(void* const* d_in, const int* in_sizes, int n_in,
                              void* d_out, int out_size, void* d_ws, size_t ws_size,
                              hipStream_t stream) {
    const float* x_body  = (const float*)d_in[0];
    const float* x_hands = (const float*)d_in[1];
    const float* x_face  = (const float*)d_in[2];
    const float* cb_body = (const float*)d_in[3];
    const float* cb_hands= (const float*)d_in[4];
    const float* cb_face = (const float*)d_in[5];
    const float* W_lin   = (const float*)d_in[6];
    const float* b_lin   = (const float*)d_in[7];
    const float* W_conv  = (const float*)d_in[8];
    const float* b_conv  = (const float*)d_in[9];
    float* out = (float*)d_out;

    float* ws = (float*)d_ws;
    float* rb    = ws;
    float* rh    = rb + RSZ;
    float* rf    = rh + RSZ;
    float* U     = rf + RSZ;
    float* hiera = U + RSZ;
    float* TC    = hiera + RSZ;              // 12 * 524288
    float* B2    = TC + 6291456;             // 512*3072
    float* cnorm = B2 + 1572864;             // 18*1024
    unsigned long long* key = (unsigned long long*)(cnorm + 18432);  // 24576 u64
    unsigned int* hist = (unsigned int*)(key + 24576);               // 18*1024

    float* outIdx  = out + 37748736;
    float* lossPtr = out + 38191104;
    float* perpPtr = out + 38191105;

    hipMemsetAsync(d_out, 0, (size_t)38191106 * 4, stream);
    hipMemsetAsync(hist, 0, 18 * 1024 * 4, stream);
    hipMemcpyAsync(rb, x_body,  (size_t)RSZ * 4, hipMemcpyDeviceToDevice, stream);
    hipMemcpyAsync(rh, x_hands, (size_t)RSZ * 4, hipMemcpyDeviceToDevice, stream);
    hipMemcpyAsync(rf, x_face,  (size_t)RSZ * 4, hipMemcpyDeviceToDevice, stream);

    k_cnorm<<<18432, 64, 0, stream>>>(cb_body, cb_hands, cb_face, cnorm);
    k_b2<<<6144, 256, 0, stream>>>(W_conv, B2);
    k_tcgemm<<<dim3(16, 8, 12), 256, 0, stream>>>(cb_body, cb_hands, W_lin, b_lin, TC);

    for (int q = 0; q < 6; ++q) {
        const float* cbq_b = cb_body  + (size_t)q * 524288;
        const float* cbq_h = cb_hands + (size_t)q * 524288;
        const float* cbq_f = cb_face  + (size_t)q * 524288;
        // ---- body VQ on rb
        hipMemsetAsync(key, 0xFF, (size_t)24576 * 8, stream);
        k_dist<<<dim3(192, 8), 256, 0, stream>>>(rb, cbq_b, cnorm + (0 * 6 + q) * 1024, key);
        k_finalize<<<96, 256, 0, stream>>>(key, outIdx, 0, q, hist + (0 * 6 + q) * 1024);
        k_update<<<384, 256, 0, stream>>>(rb, rb, cbq_b, out, 0, key, lossPtr);
        k_gatherU<<<12288, 256, 0, stream>>>(TC + (size_t)(0 * 6 + q) * 524288, key, U);
        // ---- hands: conv(concat(transform(quant_b), rh)) -> VQ
        k_conv<<<dim3(192, 4), 256, 0, stream>>>(U, rh, B2, b_conv, hiera);
        hipMemsetAsync(key, 0xFF, (size_t)24576 * 8, stream);
        k_dist<<<dim3(192, 8), 256, 0, stream>>>(hiera, cbq_h, cnorm + (1 * 6 + q) * 1024, key);
        k_finalize<<<96, 256, 0, stream>>>(key, outIdx, 1, q, hist + (1 * 6 + q) * 1024);
        k_update<<<384, 256, 0, stream>>>(hiera, rh, cbq_h, out, 512, key, lossPtr);
        k_gatherU<<<12288, 256, 0, stream>>>(TC + (size_t)(1 * 6 + q) * 524288, key, U);
        // ---- face: conv(concat(transform(quant_h), rf)) -> VQ
        k_conv<<<dim3(192, 4), 256, 0, stream>>>(U, rf, B2, b_conv, hiera);
        hipMemsetAsync(key, 0xFF, (size_t)24576 * 8, stream);
        k_dist<<<dim3(192, 8), 256, 0, stream>>>(hiera, cbq_f, cnorm + (2 * 6 + q) * 1024, key);
        k_finalize<<<96, 256, 0, stream>>>(key, outIdx, 2, q, hist + (2 * 6 + q) * 1024);
        k_update<<<384, 256, 0, stream>>>(hiera, rf, cbq_f, out, 1024, key, lossPtr);
    }
    k_perp<<<18, 256, 0, stream>>>(hist, perpPtr);
}